// Round 9
// baseline (38.212 us; speedup 1.0000x reference)
//
#include <hip/hip_runtime.h>

// out[b] = sum_h [ dot(x1_bh,W1_h) + b1_h + dot(x2_bh,W2_h)
//                  + sum_o x2_bh[o] * dot(W3_h[o,:], x1_bh) ]
// B=16384, HEAD=8, DIM=128.
//
// R9 (from R8): attack MLP starvation (all pipes <20% in R8).
//  - Hoist ALL 32 x2 epilogue loads to kernel top (32 VGPRs, in flight
//    through the whole W3-staging prologue).
//  - W3 staging via __builtin_amdgcn_global_load_lds width=16 (linear
//    float4-per-tid layout == wave-uniform base + lane*16, guide §5):
//    no staging VGPRs, no ds_writes; __syncthreads drains vmcnt.
//  - Rest identical to R8 (proven): double-buffered 2x16KB slabs, one
//    barrier per phase, head=bid&7 XCD pinning, split-bf16 3-pass numerics,
//    barrier-free shuffle epilogue, psum + reduce kernel.
// Fragment layouts (verified m89/m91): A: m=lane&15, k=(lane>>4)*8+j;
//   B: n=lane&15, same k; C/D: col=lane&15, row=(lane>>4)*4+reg.
// ws: [0,256K) whi | [256K,512K) wlo | [512K,1M) psum float[8][16384]

#define NB 16384
#define NHEAD 8
#define NDIM 128

typedef __attribute__((ext_vector_type(8))) short bf16x8;
typedef __attribute__((ext_vector_type(4))) float f32x4;

__device__ __forceinline__ void gload_lds16(const void* g, void* l) {
    __builtin_amdgcn_global_load_lds(
        (const __attribute__((address_space(1))) unsigned*)g,
        (__attribute__((address_space(3))) unsigned*)l, 16, 0, 0);
}

// ---- prep: split W3 into bf16 hi/lo in MFMA B-fragment order ----
// t = ((h*4+kk)*8+nt)*64+lane ; writes whi[t*8..t*8+8)
__global__ __launch_bounds__(256) void prep_w3(
    const float* __restrict__ W3, short* __restrict__ whi,
    short* __restrict__ wlo)
{
    const int t    = blockIdx.x * 256 + threadIdx.x;   // 16384 threads
    const int lane = t & 63;
    const int nt   = (t >> 6) & 7;
    const int kk   = (t >> 9) & 3;
    const int h    = t >> 11;
    const int lm   = lane & 15;
    const int lg   = lane >> 4;

    const float* src = W3 + ((size_t)(h * NDIM + nt * 16 + lm)) * NDIM
                          + kk * 32 + lg * 8;
    const float4 a = *reinterpret_cast<const float4*>(src);
    const float4 b = *reinterpret_cast<const float4*>(src + 4);
    float xf[8] = {a.x, a.y, a.z, a.w, b.x, b.y, b.z, b.w};
    bf16x8 hi, lo;
#pragma unroll
    for (int j = 0; j < 8; ++j) {
        const unsigned u = __float_as_uint(xf[j]);
        hi[j] = (short)(u >> 16);
        const float hf = __uint_as_float(u & 0xffff0000u);
        lo[j] = (short)(__float_as_uint(xf[j] - hf) >> 16);
    }
    reinterpret_cast<bf16x8*>(whi)[t] = hi;
    reinterpret_cast<bf16x8*>(wlo)[t] = lo;
}

// ---- main: head = bid&7, 4 waves x 16 samples = 64 samples/block ----
__global__ __launch_bounds__(256, 4) void bilinear_mfma(
    const float* __restrict__ x1, const float* __restrict__ x2,
    const float* __restrict__ W1, const float* __restrict__ W2,
    const short* __restrict__ whi, const short* __restrict__ wlo,
    float* __restrict__ psum)
{
    const int tid = threadIdx.x;
    const int w   = tid >> 6;
    const int l   = tid & 63;
    const int lm  = l & 15;
    const int lg  = l >> 4;
    const int bid = blockIdx.x;
    const int h   = bid & 7;               // head pinned per-XCD (round-robin)
    const int b0  = (bid >> 3) * 64;
    const int bw  = b0 + w * 16;           // wave's 16 samples

    __shared__ short lhi[2][4096];         // 2 x 8 KB slabs, frag order
    __shared__ short llo[2][4096];         // 2 x 8 KB

    const short* __restrict__ shi = whi + (size_t)h * 16384;
    const short* __restrict__ slo = wlo + (size_t)h * 16384;

    const float* __restrict__ w1base = W1 + h * NDIM;
    const float* __restrict__ x1base = x1 + (size_t)(bw + lm) * (NHEAD * NDIM)
                                          + h * NDIM + lg * 8;

    // ---- hoisted x2 loads: 32 dwords in flight from the very top ----
    float x2r[4][8];
    {
        const float* x2base = x2 + (size_t)(bw + lg * 4) * (NHEAD * NDIM)
                                 + h * NDIM + lm;
#pragma unroll
        for (int r = 0; r < 4; ++r)
#pragma unroll
            for (int nt = 0; nt < 8; ++nt)
                x2r[r][nt] = x2base[(size_t)r * (NHEAD * NDIM) + nt * 16];
    }

    // ---- prologue: slab 0 straight to LDS, x1 kk=0 prefetch ----
    // global float4 idx for phase kk, seg s: kk*512 + s*256 + tid (x8 shorts)
    // LDS dest (lane-uniform base): (s*256 + w*64)*8 shorts; HW adds lane*16B
    gload_lds16(shi + (size_t)(tid) * 8,        &lhi[0][(w * 64) * 8]);
    gload_lds16(shi + (size_t)(256 + tid) * 8,  &lhi[0][(256 + w * 64) * 8]);
    gload_lds16(slo + (size_t)(tid) * 8,        &llo[0][(w * 64) * 8]);
    gload_lds16(slo + (size_t)(256 + tid) * 8,  &llo[0][(256 + w * 64) * 8]);

    float4 pa = *reinterpret_cast<const float4*>(x1base);
    float4 pb = *reinterpret_cast<const float4*>(x1base + 4);

    f32x4 acc[8];
#pragma unroll
    for (int nt = 0; nt < 8; ++nt) acc[nt] = (f32x4)0.f;
    float t1 = 0.f;

    __syncthreads();   // drains vmcnt -> slab 0 + x2r + x1 ready

#pragma unroll
    for (int kk = 0; kk < 4; ++kk) {
        const int cur = kk & 1;
        const int nxt = cur ^ 1;

        // issue NEXT slab straight to LDS (flies over this phase's compute)
        if (kk < 3) {
            const size_t g0 = (size_t)((kk + 1) * 512 + tid) * 8;
            gload_lds16(shi + g0,            &lhi[nxt][(w * 64) * 8]);
            gload_lds16(shi + g0 + 256 * 8,  &lhi[nxt][(256 + w * 64) * 8]);
            gload_lds16(slo + g0,            &llo[nxt][(w * 64) * 8]);
            gload_lds16(slo + g0 + 256 * 8,  &llo[nxt][(256 + w * 64) * 8]);
        }
        const float4 ca = pa, cb = pb;
        if (kk < 3) {
            pa = *reinterpret_cast<const float4*>(x1base + (kk + 1) * 32);
            pb = *reinterpret_cast<const float4*>(x1base + (kk + 1) * 32 + 4);
        }

        // A-fragment split + t1 from exact fp32 values
        bf16x8 ahi, alo;
        {
            const int k0 = kk * 32 + lg * 8;
            const float4 wa = *reinterpret_cast<const float4*>(w1base + k0);
            const float4 wb = *reinterpret_cast<const float4*>(w1base + k0 + 4);
            float xf[8]  = {ca.x, ca.y, ca.z, ca.w, cb.x, cb.y, cb.z, cb.w};
            float w1f[8] = {wa.x, wa.y, wa.z, wa.w, wb.x, wb.y, wb.z, wb.w};
#pragma unroll
            for (int j = 0; j < 8; ++j) {
                const unsigned u = __float_as_uint(xf[j]);
                ahi[j] = (short)(u >> 16);
                const float hf = __uint_as_float(u & 0xffff0000u);
                alo[j] = (short)(__float_as_uint(xf[j] - hf) >> 16);
                t1 += xf[j] * w1f[j];
            }
        }

        // B-fragments from LDS buf[cur] (linear ds_read_b128, conflict-free)
#pragma unroll
        for (int nt = 0; nt < 8; ++nt) {
            const bf16x8 bhi = *reinterpret_cast<const bf16x8*>(
                &lhi[cur][nt * 512 + l * 8]);
            const bf16x8 blo = *reinterpret_cast<const bf16x8*>(
                &llo[cur][nt * 512 + l * 8]);
            acc[nt] = __builtin_amdgcn_mfma_f32_16x16x32_bf16(ahi, bhi, acc[nt], 0, 0, 0);
            acc[nt] = __builtin_amdgcn_mfma_f32_16x16x32_bf16(alo, bhi, acc[nt], 0, 0, 0);
            acc[nt] = __builtin_amdgcn_mfma_f32_16x16x32_bf16(ahi, blo, acc[nt], 0, 0, 0);
        }

        __syncthreads();   // drains vmcnt -> slab nxt complete; reads done
    }

    // ---- barrier-free epilogue: sum_o (P+W2[o])*x2[b,o], fold t1 ----
    float w2v[8];
#pragma unroll
    for (int nt = 0; nt < 8; ++nt) w2v[nt] = W2[h * NDIM + nt * 16 + lm];

    float cr[4];
#pragma unroll
    for (int r = 0; r < 4; ++r) {
        float s = 0.f;
#pragma unroll
        for (int nt = 0; nt < 8; ++nt)
            s += (acc[nt][r] + w2v[nt]) * x2r[r][nt];
        cr[r] = s;
    }
#pragma unroll
    for (int m = 1; m < 16; m <<= 1)
#pragma unroll
        for (int r = 0; r < 4; ++r) cr[r] += __shfl_xor(cr[r], m, 64);

    // t1: sum over lg groups -> every lane holds T(bw + (l&15))
    float tf = t1;
    tf += __shfl_xor(tf, 16, 64);
    tf += __shfl_xor(tf, 32, 64);
#pragma unroll
    for (int r = 0; r < 4; ++r) cr[r] += __shfl(tf, lg * 4 + r, 64);

    if (lm == 0) {
        float4 st;
        st.x = cr[0]; st.y = cr[1]; st.z = cr[2]; st.w = cr[3];
        *reinterpret_cast<float4*>(&psum[(size_t)h * NB + bw + lg * 4]) = st;
    }
}

__global__ __launch_bounds__(256) void bilinear_reduce(
    const float* __restrict__ psum, const float* __restrict__ b1,
    float* __restrict__ out)
{
    const int i = blockIdx.x * 256 + threadIdx.x;
    float bs = 0.f;
#pragma unroll
    for (int hh = 0; hh < NHEAD; ++hh) bs += b1[hh];
    float s = bs;
#pragma unroll
    for (int hh = 0; hh < NHEAD; ++hh) s += psum[(size_t)hh * NB + i];
    out[i] = s;
}

extern "C" void kernel_launch(void* const* d_in, const int* in_sizes, int n_in,
                              void* d_out, int out_size, void* d_ws, size_t ws_size,
                              hipStream_t stream) {
    const float* x1 = (const float*)d_in[0];
    const float* x2 = (const float*)d_in[1];
    const float* W1 = (const float*)d_in[2];
    const float* b1 = (const float*)d_in[3];
    const float* W2 = (const float*)d_in[4];
    const float* W3 = (const float*)d_in[5];
    float* out = (float*)d_out;

    short* whi = (short*)d_ws;                          // 256 KB
    short* wlo = whi + (size_t)NHEAD * NDIM * NDIM;     // 256 KB
    float* psum = (float*)((char*)d_ws + 512 * 1024);   // 512 KB

    prep_w3<<<dim3(64), dim3(256), 0, stream>>>(W3, whi, wlo);
    bilinear_mfma<<<dim3(NB / 64 * NHEAD), dim3(256), 0, stream>>>(
        x1, x2, W1, W2, whi, wlo, psum);
    bilinear_reduce<<<dim3(NB / 256), dim3(256), 0, stream>>>(psum, b1, out);
}